// Round 1
// baseline (123.309 us; speedup 1.0000x reference)
//
#include <hip/hip_runtime.h>

typedef unsigned short u16;
typedef __bf16 bf16x8 __attribute__((ext_vector_type(8)));
typedef float f32x4 __attribute__((ext_vector_type(4)));

#define B_   16
#define H_   56
#define W_   56
#define C_   128
#define OH_  54
#define OW_  54
#define NF_  256
#define KF_  1152           // C_*9
#define M_   46656          // B_*OH_*OW_
#define NNZ_ 58982

#define XB_ELEMS (B_*H_*W_*C_)       // 6422528
#define WT_ELEMS (NF_*KF_)           // 294912

__device__ __forceinline__ u16 f2bf(float f) {
    unsigned u = __float_as_uint(f);
    u += 0x7FFFu + ((u >> 16) & 1u);
    return (u16)(u >> 16);
}

__device__ __forceinline__ void gload16(const void* g, void* l) {
    __builtin_amdgcn_global_load_lds(
        (const __attribute__((address_space(1))) unsigned int*)g,
        (__attribute__((address_space(3))) unsigned int*)l,
        16, 0, 0);
}

// ---- kernel 1: x f32 -> bf16 (vectorized 8/thread) ----
__global__ __launch_bounds__(256) void cvt_x_kernel(const float* __restrict__ x,
                                                    u16* __restrict__ xb) {
    int i = (blockIdx.x * 256 + threadIdx.x) * 8;
    float4 v0 = *(const float4*)(x + i);
    float4 v1 = *(const float4*)(x + i + 4);
    union { u16 u[8]; uint4 v; } r;
    r.u[0] = f2bf(v0.x); r.u[1] = f2bf(v0.y); r.u[2] = f2bf(v0.z); r.u[3] = f2bf(v0.w);
    r.u[4] = f2bf(v1.x); r.u[5] = f2bf(v1.y); r.u[6] = f2bf(v1.z); r.u[7] = f2bf(v1.w);
    *(uint4*)(xb + i) = r.v;
}

// ---- kernel 2: scatter sparse values into dense W^T [NF][KF] bf16 ----
__global__ __launch_bounds__(256) void scatter_kernel(const float* __restrict__ kv,
                                                      const int* __restrict__ idx,
                                                      u16* __restrict__ wt) {
    int t = blockIdx.x * 256 + threadIdx.x;
    if (t >= NNZ_) return;
    int row = idx[2*t];      // k index in [0,1152)
    int col = idx[2*t + 1];  // n index in [0,256)
    wt[col * KF_ + row] = f2bf(kv[t]);
}

// ---- kernel 3: implicit-GEMM conv: out = relu(A(46656x1152) @ Wt^T + bias) ----
// BM=64 (729 blocks, exact), BN=256 (all N), BK=32, 4 waves of 64x64 each.
// LDS layout K-slot-major: tile[ks][row][8 bf16] -> conflict-free ds_read_b128
// and linear global_load_lds destinations.
__global__ __launch_bounds__(256) void spconv_gemm(const u16* __restrict__ xb,
                                                   const u16* __restrict__ wt,
                                                   const float* __restrict__ bias,
                                                   float* __restrict__ out) {
    __shared__ __align__(16) u16 As[4 * 64 * 8];    //  4 KB [ks][m][e]
    __shared__ __align__(16) u16 Bs[4 * 256 * 8];   // 16 KB [ks][col][e]

    const int t    = threadIdx.x;
    const int lane = t & 63;
    const int wid  = t >> 6;
    const int m0   = blockIdx.x * 64;

    // A staging: thread stages one 16B cell (ksA = t>>6, mA = t&63)
    const int mA  = t & 63;
    const int ksA = t >> 6;
    {
        // nothing
    }
    int mg  = m0 + mA;
    int bb  = mg / (OH_ * OW_);
    int rem = mg % (OH_ * OW_);
    int ii  = rem / OW_;
    int jj  = rem % OW_;
    const u16* a_base = xb + ((bb * H_ + ii) * W_ + jj) * C_ + ksA * 8;
    u16* a_dst = &As[(ksA * 64 + mA) * 8];

    // B staging: thread stages 4 cells (ks=0..3, col=t)
    const u16* b_base = wt + t * KF_;
    u16* b_dst = &Bs[t * 8];

    f32x4 acc[4][4];
    const f32x4 zz = {0.f, 0.f, 0.f, 0.f};
#pragma unroll
    for (int i = 0; i < 4; ++i)
#pragma unroll
        for (int j = 0; j < 4; ++j) acc[i][j] = zz;

    const int ks  = lane >> 4;
    const int r16 = lane & 15;

    for (int kt = 0; kt < 36; ++kt) {
        int g  = kt >> 2;             // (di,dj) group, 0..8
        int di = (g * 11) >> 5;       // g/3 for g<9
        int dj = g - 3 * di;
        int aoff = (di * W_ + dj) * C_ + (kt & 3) * 32;

        __syncthreads();              // previous compute done before overwrite
        gload16(a_base + aoff, a_dst);
        const u16* bsrc = b_base + kt * 32;
        gload16(bsrc,      b_dst);
        gload16(bsrc + 8,  b_dst + 2048);
        gload16(bsrc + 16, b_dst + 4096);
        gload16(bsrc + 24, b_dst + 6144);
        __syncthreads();              // drains vmcnt before barrier

        bf16x8 a[4], b[4];
#pragma unroll
        for (int mf = 0; mf < 4; ++mf)
            a[mf] = *(const bf16x8*)&As[(ks * 64 + mf * 16 + r16) * 8];
#pragma unroll
        for (int nf = 0; nf < 4; ++nf)
            b[nf] = *(const bf16x8*)&Bs[(ks * 256 + wid * 64 + nf * 16 + r16) * 8];
#pragma unroll
        for (int mf = 0; mf < 4; ++mf)
#pragma unroll
            for (int nf = 0; nf < 4; ++nf)
                acc[mf][nf] = __builtin_amdgcn_mfma_f32_16x16x32_bf16(
                    a[mf], b[nf], acc[mf][nf], 0, 0, 0);
    }

    // epilogue: C/D layout col = lane&15, row = (lane>>4)*4 + reg (m89-verified)
    const int rgrp = lane >> 4;
#pragma unroll
    for (int nf = 0; nf < 4; ++nf) {
        int col  = wid * 64 + nf * 16 + r16;
        float bv = bias[col];
#pragma unroll
        for (int mf = 0; mf < 4; ++mf) {
#pragma unroll
            for (int r = 0; r < 4; ++r) {
                int row = m0 + mf * 16 + rgrp * 4 + r;
                float v = acc[mf][nf][r] + bv;
                out[row * NF_ + col] = fmaxf(v, 0.f);
            }
        }
    }
}

extern "C" void kernel_launch(void* const* d_in, const int* in_sizes, int n_in,
                              void* d_out, int out_size, void* d_ws, size_t ws_size,
                              hipStream_t stream) {
    const float* x    = (const float*)d_in[0];
    const float* kv   = (const float*)d_in[1];
    const float* bias = (const float*)d_in[2];
    const int*   idx  = (const int*)d_in[3];
    float* out = (float*)d_out;

    u16* xb  = (u16*)d_ws;
    u16* wtp = (u16*)((char*)d_ws + (size_t)XB_ELEMS * 2);

    hipMemsetAsync(wtp, 0, (size_t)WT_ELEMS * 2, stream);
    cvt_x_kernel<<<XB_ELEMS / (256 * 8), 256, 0, stream>>>(x, xb);
    scatter_kernel<<<(NNZ_ + 255) / 256, 256, 0, stream>>>(kv, idx, wtp);
    spconv_gemm<<<M_ / 64, 256, 0, stream>>>(xb, wtp, bias, out);
}

// Round 2
// 118.996 us; speedup vs baseline: 1.0362x; 1.0362x over previous
//
#include <hip/hip_runtime.h>

typedef unsigned short u16;
typedef __bf16 bf16x8 __attribute__((ext_vector_type(8)));
typedef float f32x4 __attribute__((ext_vector_type(4)));

#define B_   16
#define H_   56
#define W_   56
#define C_   128
#define OH_  54
#define OW_  54
#define NF_  256
#define KF_  1152           // C_*9
#define M_   46656          // B_*OH_*OW_
#define NNZ_ 58982

#define XB_ELEMS (B_*H_*W_*C_)       // 6422528
#define WT_ELEMS (NF_*KF_)           // 294912

__device__ __forceinline__ u16 f2bf(float f) {
    unsigned u = __float_as_uint(f);
    u += 0x7FFFu + ((u >> 16) & 1u);
    return (u16)(u >> 16);
}

__device__ __forceinline__ void gload16(const void* g, void* l) {
    __builtin_amdgcn_global_load_lds(
        (const __attribute__((address_space(1))) unsigned int*)g,
        (__attribute__((address_space(3))) unsigned int*)l,
        16, 0, 0);
}

// ---- kernel 1: x f32 -> bf16 (vectorized 8/thread) ----
__global__ __launch_bounds__(256) void cvt_x_kernel(const float* __restrict__ x,
                                                    u16* __restrict__ xb) {
    int i = (blockIdx.x * 256 + threadIdx.x) * 8;
    float4 v0 = *(const float4*)(x + i);
    float4 v1 = *(const float4*)(x + i + 4);
    union { u16 u[8]; uint4 v; } r;
    r.u[0] = f2bf(v0.x); r.u[1] = f2bf(v0.y); r.u[2] = f2bf(v0.z); r.u[3] = f2bf(v0.w);
    r.u[4] = f2bf(v1.x); r.u[5] = f2bf(v1.y); r.u[6] = f2bf(v1.z); r.u[7] = f2bf(v1.w);
    *(uint4*)(xb + i) = r.v;
}

// ---- kernel 2: scatter sparse values into dense W^T [NF][KF] bf16 ----
__global__ __launch_bounds__(256) void scatter_kernel(const float* __restrict__ kv,
                                                      const int* __restrict__ idx,
                                                      u16* __restrict__ wt) {
    int t = blockIdx.x * 256 + threadIdx.x;
    if (t >= NNZ_) return;
    int row = idx[2*t];      // k index in [0,1152)
    int col = idx[2*t + 1];  // n index in [0,256)
    wt[col * KF_ + row] = f2bf(kv[t]);
}

// ---- kernel 3: implicit-GEMM conv, double-buffered prefetch (2-phase T3) ----
// BM=64 (729 blocks exact), BN=256, BK=32, 4 waves of 64x64.
// LDS K-slot-major [ks][row][8]: linear global_load_lds dest + conflict-free
// ds_read_b128. Prefetch tile kt+1 into buf^1 while computing buf.
__global__ __launch_bounds__(256) void spconv_gemm(const u16* __restrict__ xb,
                                                   const u16* __restrict__ wt,
                                                   const float* __restrict__ bias,
                                                   float* __restrict__ out) {
    __shared__ __align__(16) u16 As[2][4 * 64 * 8];    // 2 x 4 KB
    __shared__ __align__(16) u16 Bs[2][4 * 256 * 8];   // 2 x 16 KB

    const int t    = threadIdx.x;
    const int lane = t & 63;
    const int wid  = t >> 6;

    // bijective XCD swizzle (nwg=729, 729%8!=0 -> m204 formula)
    const int nwg = gridDim.x;
    const int q = nwg >> 3, r = nwg & 7;
    const int xcd = blockIdx.x & 7, inner = blockIdx.x >> 3;
    const int wg = (xcd < r ? xcd * (q + 1) : r * (q + 1) + (xcd - r) * q) + inner;
    const int m0 = wg * 64;

    // A staging: thread stages one 16B cell (ksA = t>>6, mA = t&63)
    const int mA  = t & 63;
    const int ksA = t >> 6;
    int mg  = m0 + mA;
    int bb  = mg / (OH_ * OW_);
    int rem = mg % (OH_ * OW_);
    int ii  = rem / OW_;
    int jj  = rem % OW_;
    const u16* a_base = xb + ((bb * H_ + ii) * W_ + jj) * C_ + ksA * 8;
    const int a_off = t * 8;          // element offset into As buffer

    // B staging: thread stages 4 cells (64B contiguous of row t)
    const u16* b_base = wt + t * KF_;
    const int b_off = t * 8;

    f32x4 acc[4][4];
    const f32x4 zz = {0.f, 0.f, 0.f, 0.f};
#pragma unroll
    for (int i = 0; i < 4; ++i)
#pragma unroll
        for (int j = 0; j < 4; ++j) acc[i][j] = zz;

    const int ks  = lane >> 4;
    const int r16 = lane & 15;

    u16* asW = &As[0][0]; u16* bsW = &Bs[0][0];   // write (stage) buffer
    u16* asR = &As[1][0]; u16* bsR = &Bs[1][0];   // read (compute) buffer

    // prologue: stage tile 0 into buffer 0
    {
        const u16* bsrc = b_base;
        gload16(a_base, asW + a_off);
        gload16(bsrc,      bsW + b_off);
        gload16(bsrc + 8,  bsW + b_off + 2048);
        gload16(bsrc + 16, bsW + b_off + 4096);
        gload16(bsrc + 24, bsW + b_off + 6144);
    }
    __syncthreads();   // drains vmcnt(0): tile 0 resident
    { u16* tmp = asW; asW = asR; asR = tmp; tmp = bsW; bsW = bsR; bsR = tmp; }

    for (int kt = 0; kt < 36; ++kt) {
        // phase 1: issue prefetch of tile kt+1 into the write buffer
        if (kt + 1 < 36) {
            int kn = kt + 1;
            int g  = kn >> 2;
            int di = (g * 11) >> 5;     // g/3 for g<9
            int dj = g - 3 * di;
            int aoff = (di * W_ + dj) * C_ + (kn & 3) * 32;
            const u16* bsrc = b_base + kn * 32;
            gload16(a_base + aoff, asW + a_off);
            gload16(bsrc,      bsW + b_off);
            gload16(bsrc + 8,  bsW + b_off + 2048);
            gload16(bsrc + 16, bsW + b_off + 4096);
            gload16(bsrc + 24, bsW + b_off + 6144);
        }

        // phase 2: compute current tile from the read buffer
        bf16x8 a[4], b[4];
#pragma unroll
        for (int mf = 0; mf < 4; ++mf)
            a[mf] = *(const bf16x8*)(asR + (ks * 64 + mf * 16 + r16) * 8);
#pragma unroll
        for (int nf = 0; nf < 4; ++nf)
            b[nf] = *(const bf16x8*)(bsR + (ks * 256 + wid * 64 + nf * 16 + r16) * 8);
#pragma unroll
        for (int mf = 0; mf < 4; ++mf)
#pragma unroll
            for (int nf = 0; nf < 4; ++nf)
                acc[mf][nf] = __builtin_amdgcn_mfma_f32_16x16x32_bf16(
                    a[mf], b[nf], acc[mf][nf], 0, 0, 0);

        // one barrier per iter: drains vmcnt (prefetch landed) + lgkm
        __syncthreads();
        { u16* tmp = asW; asW = asR; asR = tmp; tmp = bsW; bsW = bsR; bsR = tmp; }
    }

    // epilogue: C/D layout col = lane&15, row = (lane>>4)*4 + reg (m89-verified)
    const int rgrp = lane >> 4;
#pragma unroll
    for (int nf = 0; nf < 4; ++nf) {
        int col  = wid * 64 + nf * 16 + r16;
        float bv = bias[col];
#pragma unroll
        for (int mf = 0; mf < 4; ++mf) {
#pragma unroll
            for (int rr = 0; rr < 4; ++rr) {
                int row = m0 + mf * 16 + rgrp * 4 + rr;
                float v = acc[mf][nf][rr] + bv;
                out[row * NF_ + col] = fmaxf(v, 0.f);
            }
        }
    }
}

extern "C" void kernel_launch(void* const* d_in, const int* in_sizes, int n_in,
                              void* d_out, int out_size, void* d_ws, size_t ws_size,
                              hipStream_t stream) {
    const float* x    = (const float*)d_in[0];
    const float* kv   = (const float*)d_in[1];
    const float* bias = (const float*)d_in[2];
    const int*   idx  = (const int*)d_in[3];
    float* out = (float*)d_out;

    u16* xb  = (u16*)d_ws;
    u16* wtp = (u16*)((char*)d_ws + (size_t)XB_ELEMS * 2);

    hipMemsetAsync(wtp, 0, (size_t)WT_ELEMS * 2, stream);
    cvt_x_kernel<<<XB_ELEMS / (256 * 8), 256, 0, stream>>>(x, xb);
    scatter_kernel<<<(NNZ_ + 255) / 256, 256, 0, stream>>>(kv, idx, wtp);
    spconv_gemm<<<M_ / 64, 256, 0, stream>>>(xb, wtp, bias, out);
}

// Round 3
// 56.049 us; speedup vs baseline: 2.2000x; 2.1231x over previous
//
#include <hip/hip_runtime.h>

typedef unsigned short u16;
typedef __bf16 bf16x8 __attribute__((ext_vector_type(8)));
typedef float f32x4 __attribute__((ext_vector_type(4)));

#define B_   16
#define H_   56
#define W_   56
#define C_   128
#define OH_  54
#define OW_  54
#define NF_  256
#define KF_  1152           // C_*9
#define M_   46656          // B_*OH_*OW_
#define NNZ_ 58982

#define XB_ELEMS (B_*H_*W_*C_)       // 6422528
#define WT_ELEMS (36*4*256*8)        // 294912 (pre-tiled [kt][ks][col][8])

__device__ __forceinline__ u16 f2bf(float f) {
    unsigned u = __float_as_uint(f);
    u += 0x7FFFu + ((u >> 16) & 1u);
    return (u16)(u >> 16);
}

__device__ __forceinline__ void gload16(const void* g, void* l) {
    __builtin_amdgcn_global_load_lds(
        (const __attribute__((address_space(1))) unsigned int*)g,
        (__attribute__((address_space(3))) unsigned int*)l,
        16, 0, 0);
}

// ---- kernel 1: x f32 -> bf16 (vectorized 8/thread) ----
__global__ __launch_bounds__(256) void cvt_x_kernel(const float* __restrict__ x,
                                                    u16* __restrict__ xb) {
    int i = (blockIdx.x * 256 + threadIdx.x) * 8;
    float4 v0 = *(const float4*)(x + i);
    float4 v1 = *(const float4*)(x + i + 4);
    union { u16 u[8]; uint4 v; } r;
    r.u[0] = f2bf(v0.x); r.u[1] = f2bf(v0.y); r.u[2] = f2bf(v0.z); r.u[3] = f2bf(v0.w);
    r.u[4] = f2bf(v1.x); r.u[5] = f2bf(v1.y); r.u[6] = f2bf(v1.z); r.u[7] = f2bf(v1.w);
    *(uint4*)(xb + i) = r.v;
}

// ---- kernel 2: scatter sparse values into PRE-TILED W: [kt][ks][col][8] ----
// k = kt*32 + ks*8 + e. Each 16KB K-tile of W is contiguous, in LDS image order.
__global__ __launch_bounds__(256) void scatter_kernel(const float* __restrict__ kv,
                                                      const int* __restrict__ idx,
                                                      u16* __restrict__ wt) {
    int t = blockIdx.x * 256 + threadIdx.x;
    if (t >= NNZ_) return;
    int k   = idx[2*t];      // row in [0,1152)
    int col = idx[2*t + 1];  // col in [0,256)
    int kt = k >> 5, ks = (k >> 3) & 3, e = k & 7;
    wt[(kt * 4 + ks) * 2048 + col * 8 + e] = f2bf(kv[t]);
}

// ---- kernel 3: implicit-GEMM conv, double-buffered, COALESCED staging ----
// BM=64 (729 blocks exact), BN=256, BK=32, 4 waves of 64x64.
// B: pre-tiled global -> lane-linear 1KB/instr, LDS [ks][col][8] (0-conflict).
// A: 4 lanes/row (64B sector each), LDS [row][32] with 2-bit XOR kc-swizzle
//    applied on the global SOURCE (dest stays linear per gload_lds rules).
__global__ __launch_bounds__(256) void spconv_gemm(const u16* __restrict__ xb,
                                                   const u16* __restrict__ wt,
                                                   const float* __restrict__ bias,
                                                   float* __restrict__ out) {
    __shared__ __align__(16) u16 As[2][64 * 32];      // 2 x 4 KB
    __shared__ __align__(16) u16 Bs[2][4 * 256 * 8];  // 2 x 16 KB

    const int t    = threadIdx.x;
    const int lane = t & 63;
    const int wid  = t >> 6;

    // bijective XCD swizzle (nwg=729, 729%8!=0 -> m204 formula)
    const int nwg = gridDim.x;
    const int q = nwg >> 3, r = nwg & 7;
    const int xcd = blockIdx.x & 7, inner = blockIdx.x >> 3;
    const int wg = (xcd < r ? xcd * (q + 1) : r * (q + 1) + (xcd - r) * q) + inner;
    const int m0 = wg * 64;

    // A staging: thread t stages cell t = (arow, kc); 4 lanes cover one row's
    // 64B K-slice. Source kc pre-swizzled; LDS dest linear.
    const int arow = (wid << 4) | (lane >> 2);          // 0..63
    const int kc   = lane & 3;
    const int kcs  = kc ^ (arow & 3) ^ ((arow >> 2) & 3);
    const int kco  = kcs * 8;                           // element offset
    int mg  = m0 + arow;
    int bb  = mg / (OH_ * OW_);
    int rem = mg % (OH_ * OW_);
    int ii  = rem / OW_;
    int jj  = rem % OW_;
    const u16* a_base = xb + ((bb * H_ + ii) * W_ + jj) * C_;
    const int a_dst = t * 8;

    // B staging: thread t stages 4 contiguous-cell chunks of the pre-tiled W
    const int b_dst = t * 8;

    f32x4 acc[4][4];
    const f32x4 zz = {0.f, 0.f, 0.f, 0.f};
#pragma unroll
    for (int i = 0; i < 4; ++i)
#pragma unroll
        for (int j = 0; j < 4; ++j) acc[i][j] = zz;

    const int ks  = lane >> 4;
    const int r16 = lane & 15;

    u16* asW = &As[0][0]; u16* bsW = &Bs[0][0];   // stage buffer
    u16* asR = &As[1][0]; u16* bsR = &Bs[1][0];   // compute buffer

    // prologue: stage tile 0 (g=0 -> di=dj=0)
    {
        gload16(a_base + kco, asW + a_dst);
        const u16* bsrc = wt + t * 8;
#pragma unroll
        for (int j = 0; j < 4; ++j)
            gload16(bsrc + j * 2048, bsW + b_dst + j * 2048);
    }
    __syncthreads();
    { u16* tmp = asW; asW = asR; asR = tmp; tmp = bsW; bsW = bsR; bsR = tmp; }

    for (int kt = 0; kt < 36; ++kt) {
        // phase 1: issue prefetch of tile kt+1
        if (kt + 1 < 36) {
            int kn = kt + 1;
            int g  = kn >> 2;
            int di = (g * 11) >> 5;     // g/3 for g<9
            int dj = g - 3 * di;
            int aoff = (di * W_ + dj) * C_ + (kn & 3) * 32 + kco;
            gload16(a_base + aoff, asW + a_dst);
            const u16* bsrc = wt + kn * 8192 + t * 8;
#pragma unroll
            for (int j = 0; j < 4; ++j)
                gload16(bsrc + j * 2048, bsW + b_dst + j * 2048);
        }

        // phase 2: compute current tile
        bf16x8 a[4], b[4];
#pragma unroll
        for (int mf = 0; mf < 4; ++mf) {
            int row  = mf * 16 + r16;
            int cidx = ks ^ (row & 3) ^ ((row >> 2) & 3);
            a[mf] = *(const bf16x8*)(asR + row * 32 + cidx * 8);
        }
#pragma unroll
        for (int nf = 0; nf < 4; ++nf)
            b[nf] = *(const bf16x8*)(bsR + (ks * 256 + wid * 64 + nf * 16 + r16) * 8);
#pragma unroll
        for (int mf = 0; mf < 4; ++mf)
#pragma unroll
            for (int nf = 0; nf < 4; ++nf)
                acc[mf][nf] = __builtin_amdgcn_mfma_f32_16x16x32_bf16(
                    a[mf], b[nf], acc[mf][nf], 0, 0, 0);

        // one barrier per iter: drains vmcnt (prefetch landed) + lgkm
        __syncthreads();
        { u16* tmp = asW; asW = asR; asR = tmp; tmp = bsW; bsW = bsR; bsR = tmp; }
    }

    // epilogue: C/D layout col = lane&15, row = (lane>>4)*4 + reg (m89-verified)
    const int rgrp = lane >> 4;
#pragma unroll
    for (int nf = 0; nf < 4; ++nf) {
        int col  = wid * 64 + nf * 16 + r16;
        float bv = bias[col];
#pragma unroll
        for (int mf = 0; mf < 4; ++mf) {
#pragma unroll
            for (int rr = 0; rr < 4; ++rr) {
                int row = m0 + mf * 16 + rgrp * 4 + rr;
                float v = acc[mf][nf][rr] + bv;
                out[row * NF_ + col] = fmaxf(v, 0.f);
            }
        }
    }
}

extern "C" void kernel_launch(void* const* d_in, const int* in_sizes, int n_in,
                              void* d_out, int out_size, void* d_ws, size_t ws_size,
                              hipStream_t stream) {
    const float* x    = (const float*)d_in[0];
    const float* kv   = (const float*)d_in[1];
    const float* bias = (const float*)d_in[2];
    const int*   idx  = (const int*)d_in[3];
    float* out = (float*)d_out;

    u16* xb  = (u16*)d_ws;
    u16* wtp = (u16*)((char*)d_ws + (size_t)XB_ELEMS * 2);

    hipMemsetAsync(wtp, 0, (size_t)WT_ELEMS * 2, stream);
    cvt_x_kernel<<<XB_ELEMS / (256 * 8), 256, 0, stream>>>(x, xb);
    scatter_kernel<<<(NNZ_ + 255) / 256, 256, 0, stream>>>(kv, idx, wtp);
    spconv_gemm<<<M_ / 64, 256, 0, stream>>>(xb, wtp, bias, out);
}